// Round 8
// baseline (2656.815 us; speedup 1.0000x reference)
//
#include <hip/hip_runtime.h>

#define H 128
typedef unsigned short u16;
typedef unsigned long long u64;
typedef __attribute__((ext_vector_type(8))) short bf16x8;
typedef __attribute__((ext_vector_type(4))) float f32x4;

__device__ __forceinline__ u16 f2b(float f) {
    unsigned u = __builtin_bit_cast(unsigned, f);
    unsigned r = (u + 0x7fff + ((u >> 16) & 1)) >> 16;
    return (u16)r;
}
__device__ __forceinline__ float b2f(u16 b) {
    unsigned u = ((unsigned)b) << 16;
    return __builtin_bit_cast(float, u);
}

// ---------------- cast f32 -> bf16 ----------------
__global__ void cast_kernel(const float* __restrict__ in, u16* __restrict__ out, long n4) {
    long stride = (long)gridDim.x * blockDim.x;
    for (long i = (long)blockIdx.x * blockDim.x + threadIdx.x; i < n4; i += stride) {
        float4 v = reinterpret_cast<const float4*>(in)[i];
        ushort4 o;
        o.x = f2b(v.x); o.y = f2b(v.y); o.z = f2b(v.z); o.w = f2b(v.w);
        reinterpret_cast<ushort4*>(out)[i] = o;
    }
}

// ---------------- pack weights into MFMA B-fragment layout (bf16) ----------------
__global__ void pack_kernel(const float* __restrict__ Wl, const float* __restrict__ Wr,
                            u16* __restrict__ out) {
    int tid = blockIdx.x * blockDim.x + threadIdx.x;  // 16*16384
    int e = tid & 16383;
    int job = tid >> 14;
    int l = job >> 3, m = job & 7;
    int lane = (e >> 3) & 63;
    int j = e & 7;
    int knb = e >> 9;  // 0..31
    int k = (knb >> 3) * 32 + ((lane >> 4) & 3) * 8 + j;
    int n = (knb & 7) * 16 + (lane & 15);
    long off = (long)k * H + n;
    float v;
    if (m < 3) v = Wl[((long)(l * 5 + m)) * (H * H) + off];
    else if (m == 3) v = Wr[((long)(l * 5 + 0)) * (H * H) + off] +
                         Wr[((long)(l * 5 + 1)) * (H * H) + off] +
                         Wr[((long)(l * 5 + 2)) * (H * H) + off];
    else if (m == 4) v = Wl[((long)(l * 5 + 3)) * (H * H) + off];
    else if (m == 5) v = Wr[((long)(l * 5 + 3)) * (H * H) + off];
    else if (m == 6) v = Wl[((long)(l * 5 + 4)) * (H * H) + off];
    else             v = Wr[((long)(l * 5 + 4)) * (H * H) + off];
    out[(long)job * 16384 + e] = f2b(v);
}

// ---------------- paper bias sums ----------------
__global__ void bsum_kernel(const float* __restrict__ bl, float* __restrict__ bsum_p) {
    int t = threadIdx.x;  // 256
    int l = t >> 7, i = t & 127;
    bsum_p[t] = bl[(long)(l * 5 + 0) * H + i] + bl[(long)(l * 5 + 1) * H + i] +
                bl[(long)(l * 5 + 2) * H + i];
}

// ---------------- combined CSR build over 5 concatenated relations ----------------
#define NPC 200000
#define NAC 100000
#define NVC 10000
#define EWC 2000000
#define EPC 200000
#define ETOT 6400000
#define NDEG 710000
#define CPAD 16        // one 64B line per cursor
#define NCB 256        // coarse buckets
#define CBW 2774       // nodes per coarse bucket (256*2774 >= NDEG)
#define EPB 25000      // edges per pass1 block (256*25000 == ETOT)

__device__ __forceinline__ void edge_map(long e, const int* w, const int* c, const int* p,
                                         const int* rw, const int* rp2, int half,
                                         int& val, int& bse) {
    // half 0: src, half 1: dst
    if (e < 2 * EWC) {
        if (e < EWC) { val = w[e + (long)half * EWC]; bse = 0; }
        else { val = c[(e - EWC) + (long)half * EWC]; bse = NPC; }
    } else if (e < 2 * EWC + EPC) {
        val = p[(e - 2 * EWC) + (long)half * EPC]; bse = 2 * NPC;
    } else if (e < 3 * EWC + EPC) {
        val = rw[(e - 2 * EWC - EPC) + (long)half * EWC]; bse = 3 * NPC;
    } else {
        val = rp2[(e - 3 * EWC - EPC) + (long)half * EPC]; bse = 3 * NPC + NAC;
    }
}

// ---- coarse histogram (LDS-staged) ----
__global__ void coarse_hist(const int* __restrict__ w, const int* __restrict__ c,
                            const int* __restrict__ p, const int* __restrict__ rw,
                            const int* __restrict__ rp2, int* __restrict__ ccnt) {
    __shared__ int h[NCB];
    int t = threadIdx.x;
    h[t] = 0;
    __syncthreads();
    long stride = (long)gridDim.x * blockDim.x;
    for (long e = (long)blockIdx.x * blockDim.x + t; e < ETOT; e += stride) {
        int d, b;
        edge_map(e, w, c, p, rw, rp2, 1, d, b);
        atomicAdd(&h[(b + d) / CBW], 1);
    }
    __syncthreads();
    if (h[t]) atomicAdd(&ccnt[t * CPAD], h[t]);
}

// ---- scan of 256 coarse counts -> cbase, init gcur ----
__global__ void scan256(const int* __restrict__ ccnt, int* __restrict__ cbase,
                        int* __restrict__ gcur) {
    __shared__ int s[NCB];
    int t = threadIdx.x;
    int own = ccnt[t * CPAD];
    s[t] = own;
    __syncthreads();
    for (int o = 1; o < NCB; o <<= 1) {
        int v = (t >= o) ? s[t - o] : 0;
        __syncthreads();
        s[t] += v;
        __syncthreads();
    }
    int excl = s[t] - own;
    cbase[t] = excl;
    gcur[t * CPAD] = excl;
    if (t == NCB - 1) cbase[NCB] = s[t];  // == ETOT
}

// ---- pass1: LDS-staged chunk partition into 256 coarse bucket streams ----
__global__ __launch_bounds__(256) void part_pass1(
    const int* __restrict__ w, const int* __restrict__ c, const int* __restrict__ p,
    const int* __restrict__ rw, const int* __restrict__ rp2,
    int* __restrict__ gcur, u64* __restrict__ binned) {
    __shared__ u64 ent[256];
    __shared__ unsigned bmap[NCB][9];   // 8 words used, pad for banks
    __shared__ u64 stage[NCB][17];      // 16 used, pad for banks
    __shared__ int scnt[NCB];

    int t = threadIdx.x;
    scnt[t] = 0;
#pragma unroll
    for (int i = 0; i < 8; ++i) bmap[t][i] = 0;
    __syncthreads();

    long base = (long)blockIdx.x * EPB;
    long eend = base + EPB;
    int nr = (EPB + 255) / 256;
    for (int r = 0; r < nr; ++r) {
        long e = base + (long)r * 256 + t;
        if (e < eend) {
            int d, b, s, b2;
            edge_map(e, w, c, p, rw, rp2, 1, d, b);
            edge_map(e, w, c, p, rw, rp2, 0, s, b2);
            int g = b + d;
            int cb = g / CBW;
            ent[t] = ((u64)(unsigned)g << 32) | (unsigned)s;
            atomicOr(&bmap[cb][t >> 5], 1u << (t & 31));
        }
        __syncthreads();
        // owner drain: thread t owns bucket t
        int cnt = scnt[t];
#pragma unroll
        for (int wd = 0; wd < 8; ++wd) {
            unsigned bits = bmap[t][wd];
            if (bits) bmap[t][wd] = 0;
            while (bits) {
                int i = __ffs(bits) - 1;
                bits &= bits - 1;
                stage[t][cnt++] = ent[wd * 32 + i];
                if (cnt == 16) {
                    int pos = atomicAdd(&gcur[t * CPAD], 16);
#pragma unroll
                    for (int k = 0; k < 16; ++k) binned[pos + k] = stage[t][k];
                    cnt = 0;
                }
            }
        }
        scnt[t] = cnt;
        __syncthreads();
    }
    int cnt = scnt[t];
    if (cnt > 0) {
        int pos = atomicAdd(&gcur[t * CPAD], cnt);
        for (int k = 0; k < cnt; ++k) binned[pos + k] = stage[t][k];
    }
}

// ---- pass2: per coarse bucket: LDS hist + scan -> row_ptr, then place srcs ----
__global__ __launch_bounds__(256) void part_pass2(
    const u64* __restrict__ binned, const int* __restrict__ cbase,
    const int* __restrict__ gcur, int* __restrict__ gscan, int* __restrict__ srcs_all) {
    __shared__ int cnt[CBW];
    __shared__ int exc[CBW];
    __shared__ int psum[256];
    int cb = blockIdx.x, t = threadIdx.x;
    int n0 = cb * CBW;
    int n1 = n0 + CBW;
    if (n1 > NDEG) n1 = NDEG;
    int nn = n1 - n0;
    for (int i = t; i < nn; i += 256) cnt[i] = 0;
    __syncthreads();
    int e0 = cbase[cb], e1 = gcur[cb * CPAD];
    for (int e = e0 + t; e < e1; e += 256) {
        int g = (int)(binned[e] >> 32);
        atomicAdd(&cnt[g - n0], 1);
    }
    __syncthreads();
    // local scan: thread t owns slots [t*11, t*11+11)
    int o0 = t * 11;
    int s = 0;
#pragma unroll
    for (int k = 0; k < 11; ++k) {
        int i = o0 + k;
        int v = (i < nn) ? cnt[i] : 0;
        if (i < CBW) exc[i] = s;
        s += v;
    }
    psum[t] = s;
    __syncthreads();
    for (int o = 1; o < 256; o <<= 1) {
        int v = (t >= o) ? psum[t - o] : 0;
        __syncthreads();
        psum[t] += v;
        __syncthreads();
    }
    int eoff = psum[t] - s;
#pragma unroll
    for (int k = 0; k < 11; ++k) {
        int i = o0 + k;
        if (i < CBW) exc[i] += eoff;
    }
    __syncthreads();
    for (int i = t; i < nn; i += 256) {
        gscan[n0 + i] = e0 + exc[i];
        cnt[i] = 0;
    }
    if (cb == gridDim.x - 1 && t == 0) gscan[NDEG] = ETOT;
    __syncthreads();
    for (int e = e0 + t; e < e1; e += 256) {
        u64 v = binned[e];
        int g = (int)(v >> 32);
        int s2 = (int)(v & 0xffffffffu);
        int loc = g - n0;
        int pos = atomicAdd(&cnt[loc], 1);
        srcs_all[e0 + exc[loc] + pos] = s2;
    }
}

// ---------------- gather mean (bf16), 4 rows per VMEM request ----------------
__global__ void gather_mean4(const u16* __restrict__ xs,
                             const int* __restrict__ rp,
                             const int* __restrict__ ss,
                             u16* __restrict__ out, int n_dst) {
    long gid = (long)blockIdx.x * blockDim.x + threadIdx.x;
    int w = (int)(gid >> 6);
    if (w >= n_dst) return;
    int lane = (int)(gid & 63);
    int q = lane >> 4, l16 = lane & 15;
    int beg = rp[w], end = rp[w + 1];

    float ax[8];
#pragma unroll
    for (int i = 0; i < 8; ++i) ax[i] = 0.f;

    for (int c = beg; c < end; c += 64) {
        int m = end - c;
        if (m > 64) m = 64;
        int idx = (lane < m) ? ss[c + lane] : 0;
        for (int jj = 0; jj < m; jj += 4) {
            int s = __shfl(idx, jj + q, 64);
            if (jj + q < m) {
                const uint4 v = *reinterpret_cast<const uint4*>(xs + (long)s * H + l16 * 8);
                ax[0] += b2f((u16)(v.x & 0xffff)); ax[1] += b2f((u16)(v.x >> 16));
                ax[2] += b2f((u16)(v.y & 0xffff)); ax[3] += b2f((u16)(v.y >> 16));
                ax[4] += b2f((u16)(v.z & 0xffff)); ax[5] += b2f((u16)(v.z >> 16));
                ax[6] += b2f((u16)(v.w & 0xffff)); ax[7] += b2f((u16)(v.w >> 16));
            }
        }
    }
#pragma unroll
    for (int i = 0; i < 8; ++i) {
        ax[i] += __shfl_xor(ax[i], 32, 64);
        ax[i] += __shfl_xor(ax[i], 16, 64);
    }
    if (q == 0) {
        float inv = 1.0f / fmaxf((float)(end - beg), 1.0f);
        uint4 o;
        o.x = (unsigned)f2b(ax[0] * inv) | ((unsigned)f2b(ax[1] * inv) << 16);
        o.y = (unsigned)f2b(ax[2] * inv) | ((unsigned)f2b(ax[3] * inv) << 16);
        o.z = (unsigned)f2b(ax[4] * inv) | ((unsigned)f2b(ax[5] * inv) << 16);
        o.w = (unsigned)f2b(ax[6] * inv) | ((unsigned)f2b(ax[7] * inv) << 16);
        *reinterpret_cast<uint4*>(out + (long)w * H + l16 * 8) = o;
    }
}

// ---------------- multi-source MFMA GEMM: acc = sum_s A_s @ W_s (+Yin), epilogue ----------------
__global__ __launch_bounds__(256) void mfma_gemm_multi(
    int n_dst, int nsrc,
    const u16* __restrict__ A0, const u16* __restrict__ W0,
    const u16* __restrict__ A1, const u16* __restrict__ W1,
    const u16* __restrict__ A2, const u16* __restrict__ W2,
    const u16* __restrict__ A3, const u16* __restrict__ W3,
    const float* __restrict__ bias, float scale,
    const float* __restrict__ Yin, float* __restrict__ Yraw,
    float* __restrict__ yf, u16* __restrict__ yb) {
    const int t = threadIdx.x;
    const int lane = t & 63;
    const int w = t >> 6;
    const int wr = w >> 1, wc = w & 1;
    const long base = (long)blockIdx.x * 128;
    const int hi = (lane >> 4) & 3;
    const int lo = lane & 15;

    f32x4 acc[4][4];
#pragma unroll
    for (int i = 0; i < 4; ++i)
#pragma unroll
        for (int j = 0; j < 4; ++j) acc[i][j] = (f32x4){0.f, 0.f, 0.f, 0.f};

    for (int p = 0; p < nsrc; ++p) {
        const u16* A = (p == 0) ? A0 : (p == 1) ? A1 : (p == 2) ? A2 : A3;
        const u16* W = (p == 0) ? W0 : (p == 1) ? W1 : (p == 2) ? W2 : W3;
#pragma unroll
        for (int ks = 0; ks < 4; ++ks) {
            bf16x8 a[4];
#pragma unroll
            for (int fr = 0; fr < 4; ++fr) {
                long r = base + wr * 64 + fr * 16 + lo;
                a[fr] = *reinterpret_cast<const bf16x8*>(A + r * H + ks * 32 + hi * 8);
            }
#pragma unroll
            for (int fc = 0; fc < 4; ++fc) {
                int nb = wc * 4 + fc;
                bf16x8 b = *reinterpret_cast<const bf16x8*>(W + ((ks * 8 + nb) * 512 + lane * 8));
#pragma unroll
                for (int fr = 0; fr < 4; ++fr)
                    acc[fr][fc] = __builtin_amdgcn_mfma_f32_16x16x32_bf16(a[fr], b, acc[fr][fc], 0, 0, 0);
            }
        }
    }

#pragma unroll
    for (int fc = 0; fc < 4; ++fc) {
        int col = wc * 64 + fc * 16 + lo;
#pragma unroll
        for (int fr = 0; fr < 4; ++fr) {
#pragma unroll
            for (int i = 0; i < 4; ++i) {
                long g = base + wr * 64 + fr * 16 + hi * 4 + i;
                if (g < n_dst) {
                    float v = acc[fr][fc][i];
                    if (Yin) v += Yin[g * H + col];
                    if (Yraw) {
                        Yraw[g * H + col] = v;
                    } else {
                        float val = fmaxf((v + bias[col]) * scale, 0.f);
                        if (yf) yf[g * H + col] = val;
                        else    yb[g * H + col] = f2b(val);
                    }
                }
            }
        }
    }
}

extern "C" void kernel_launch(void* const* d_in, const int* in_sizes, int n_in,
                              void* d_out, int out_size, void* d_ws, size_t ws_size,
                              hipStream_t stream) {
    const float* xp0 = (const float*)d_in[0];
    const float* xa0 = (const float*)d_in[1];
    const float* xv0 = (const float*)d_in[2];
    const float* Wl  = (const float*)d_in[3];
    const float* bl  = (const float*)d_in[4];
    const float* Wr  = (const float*)d_in[5];
    const int* ei_w  = (const int*)d_in[6];
    const int* ei_c  = (const int*)d_in[7];
    const int* ei_p  = (const int*)d_in[8];
    const int* ei_rw = (const int*)d_in[9];
    const int* ei_rp = (const int*)d_in[10];

    const long NP = 200000, NA = 100000, NV = 10000;
    const long NPp = 200064, NAp = 100096, NVp = 10112;

    const size_t NEED_FULL = 344316508 + 4096;
    const bool full = ws_size >= NEED_FULL;

    char* cur = (char*)d_ws;
    auto alloc = [&](long bytes) { char* r = cur; cur += (bytes + 255) & ~255L; return r; };
    u16* xpb   = (u16*)alloc(NPp * H * 2);
    u16* xab   = (u16*)alloc(NAp * H * 2);
    u16* xvb   = (u16*)alloc(NVp * H * 2);
    u16* xp1b  = (u16*)alloc(NPp * H * 2);
    u16* xa1b  = (u16*)alloc(NAp * H * 2);
    u16* xv1b  = (u16*)alloc(NVp * H * 2);
    u16* agg0  = (u16*)alloc(NPp * H * 2);
    u16* agg1  = full ? (u16*)alloc(NPp * H * 2) : nullptr;
    u16* agg2  = full ? (u16*)alloc(NPp * H * 2) : nullptr;
    u16* packw = (u16*)alloc(16 * 16384 * 2);
    float* bsum_p = (float*)alloc(256 * 4);
    int* gscan    = (int*)alloc((NDEG + 1) * 4);
    int* deg      = (int*)alloc(NDEG * 4);       // carved below
    int* srcs_all = (int*)alloc((long)ETOT * 4);
    int* bsums    = (int*)alloc(((NDEG + 1023) / 1024) * 4);  // unused, kept for layout
    (void)bsums;

    // carve small arrays out of dead 'deg' region (2.84 MB >> 34 KB needed)
    int* gcur  = deg;                       // [NCB*CPAD]
    int* cbase = deg + NCB * CPAD;          // [NCB+1]
    int* ccnt  = deg + NCB * CPAD + 272;    // [NCB*CPAD]
    // binned aliases agg0 (dead during CSR build): ETOT*8 = 51.2 MB <= 51.22 MB
    u64* binned = (u64*)agg0;

    float* op = (float*)d_out;
    float* oa = op + NP * H;
    float* ov = oa + NA * H;

    // ---- prep: casts, weight pack, bias sums ----
    cast_kernel<<<2048, 256, 0, stream>>>(xp0, xpb, NP * H / 4);
    cast_kernel<<<1024, 256, 0, stream>>>(xa0, xab, NA * H / 4);
    cast_kernel<<<256, 256, 0, stream>>>(xv0, xvb, NV * H / 4);
    pack_kernel<<<1024, 256, 0, stream>>>(Wl, Wr, packw);
    bsum_kernel<<<1, 256, 0, stream>>>(bl, bsum_p);

    // ---- CSR build: coarse hist -> scan -> chunked partition -> local sort ----
    hipMemsetAsync(ccnt, 0, NCB * CPAD * 4, stream);
    coarse_hist<<<1024, 256, 0, stream>>>(ei_w, ei_c, ei_p, ei_rw, ei_rp, ccnt);
    scan256<<<1, 256, 0, stream>>>(ccnt, cbase, gcur);
    part_pass1<<<256, 256, 0, stream>>>(ei_w, ei_c, ei_p, ei_rw, ei_rp, gcur, binned);
    part_pass2<<<NCB, 256, 0, stream>>>(binned, cbase, gcur, gscan, srcs_all);

    const int* rp_w  = gscan;
    const int* rp_c  = gscan + NP;
    const int* rp_p  = gscan + 2 * NP;
    const int* rp_rw = gscan + 3 * NP;
    const int* rp_rp = gscan + 3 * NP + NA;

    auto PW = [&](int l, int m) { return packw + (long)(l * 8 + m) * 16384; };
    auto GV = [&](long n) { return (int)((n * 64 + 255) / 256); };
    auto GT = [&](long np) { return (int)(np / 128); };
    const u16* NU = nullptr;

    auto run_layer = [&](int l, const u16* xp, const u16* xa, const u16* xv,
                         float* Yp, float* yfp, u16* ybp,
                         float* yfa, u16* yba, float* yfv, u16* ybv) {
        if (full) {
            gather_mean4<<<GV(NP), 256, 0, stream>>>(xa, rp_w, srcs_all, agg0, (int)NP);
            gather_mean4<<<GV(NP), 256, 0, stream>>>(xp, rp_c, srcs_all, agg1, (int)NP);
            gather_mean4<<<GV(NP), 256, 0, stream>>>(xv, rp_p, srcs_all, agg2, (int)NP);
            mfma_gemm_multi<<<GT(NPp), 256, 0, stream>>>(
                (int)NP, 4, xp, PW(l, 3), agg0, PW(l, 0), agg1, PW(l, 1), agg2, PW(l, 2),
                bsum_p + l * 128, 1.0f / 3.0f, nullptr, nullptr, yfp, ybp);
        } else {
            gather_mean4<<<GV(NP), 256, 0, stream>>>(xa, rp_w, srcs_all, agg0, (int)NP);
            mfma_gemm_multi<<<GT(NPp), 256, 0, stream>>>(
                (int)NP, 2, xp, PW(l, 3), agg0, PW(l, 0), NU, NU, NU, NU,
                nullptr, 0.f, nullptr, Yp, nullptr, nullptr);
            gather_mean4<<<GV(NP), 256, 0, stream>>>(xp, rp_c, srcs_all, agg0, (int)NP);
            mfma_gemm_multi<<<GT(NPp), 256, 0, stream>>>(
                (int)NP, 1, agg0, PW(l, 1), NU, NU, NU, NU, NU, NU,
                nullptr, 0.f, Yp, Yp, nullptr, nullptr);
            gather_mean4<<<GV(NP), 256, 0, stream>>>(xv, rp_p, srcs_all, agg0, (int)NP);
            mfma_gemm_multi<<<GT(NPp), 256, 0, stream>>>(
                (int)NP, 1, agg0, PW(l, 2), NU, NU, NU, NU, NU, NU,
                bsum_p + l * 128, 1.0f / 3.0f, Yp, nullptr, yfp, ybp);
        }
        gather_mean4<<<GV(NA), 256, 0, stream>>>(xp, rp_rw, srcs_all, agg0, (int)NA);
        mfma_gemm_multi<<<GT(NAp), 256, 0, stream>>>(
            (int)NA, 2, xa, PW(l, 5), agg0, PW(l, 4), NU, NU, NU, NU,
            bl + (long)(l * 5 + 3) * H, 1.0f, nullptr, nullptr, yfa, yba);
        gather_mean4<<<GV(NV), 256, 0, stream>>>(xp, rp_rp, srcs_all, agg0, (int)NV);
        mfma_gemm_multi<<<GT(NVp), 256, 0, stream>>>(
            (int)NV, 2, xv, PW(l, 7), agg0, PW(l, 6), NU, NU, NU, NU,
            bl + (long)(l * 5 + 4) * H, 1.0f, nullptr, nullptr, yfv, ybv);
    };

    run_layer(0, xpb, xab, xvb, op, nullptr, xp1b, nullptr, xa1b, nullptr, xv1b);
    run_layer(1, xp1b, xa1b, xv1b, op, op, nullptr, oa, nullptr, ov, nullptr);
}

// Round 9
// 1748.842 us; speedup vs baseline: 1.5192x; 1.5192x over previous
//
#include <hip/hip_runtime.h>

#define H 128
typedef unsigned short u16;
typedef unsigned long long u64;
typedef __attribute__((ext_vector_type(8))) short bf16x8;
typedef __attribute__((ext_vector_type(4))) float f32x4;

__device__ __forceinline__ u16 f2b(float f) {
    unsigned u = __builtin_bit_cast(unsigned, f);
    unsigned r = (u + 0x7fff + ((u >> 16) & 1)) >> 16;
    return (u16)r;
}
__device__ __forceinline__ float b2f(u16 b) {
    unsigned u = ((unsigned)b) << 16;
    return __builtin_bit_cast(float, u);
}

// ---------------- cast f32 -> bf16 ----------------
__global__ void cast_kernel(const float* __restrict__ in, u16* __restrict__ out, long n4) {
    long stride = (long)gridDim.x * blockDim.x;
    for (long i = (long)blockIdx.x * blockDim.x + threadIdx.x; i < n4; i += stride) {
        float4 v = reinterpret_cast<const float4*>(in)[i];
        ushort4 o;
        o.x = f2b(v.x); o.y = f2b(v.y); o.z = f2b(v.z); o.w = f2b(v.w);
        reinterpret_cast<ushort4*>(out)[i] = o;
    }
}

// ---------------- pack weights into MFMA B-fragment layout (bf16) ----------------
__global__ void pack_kernel(const float* __restrict__ Wl, const float* __restrict__ Wr,
                            u16* __restrict__ out) {
    int tid = blockIdx.x * blockDim.x + threadIdx.x;  // 16*16384
    int e = tid & 16383;
    int job = tid >> 14;
    int l = job >> 3, m = job & 7;
    int lane = (e >> 3) & 63;
    int j = e & 7;
    int knb = e >> 9;  // 0..31
    int k = (knb >> 3) * 32 + ((lane >> 4) & 3) * 8 + j;
    int n = (knb & 7) * 16 + (lane & 15);
    long off = (long)k * H + n;
    float v;
    if (m < 3) v = Wl[((long)(l * 5 + m)) * (H * H) + off];
    else if (m == 3) v = Wr[((long)(l * 5 + 0)) * (H * H) + off] +
                         Wr[((long)(l * 5 + 1)) * (H * H) + off] +
                         Wr[((long)(l * 5 + 2)) * (H * H) + off];
    else if (m == 4) v = Wl[((long)(l * 5 + 3)) * (H * H) + off];
    else if (m == 5) v = Wr[((long)(l * 5 + 3)) * (H * H) + off];
    else if (m == 6) v = Wl[((long)(l * 5 + 4)) * (H * H) + off];
    else             v = Wr[((long)(l * 5 + 4)) * (H * H) + off];
    out[(long)job * 16384 + e] = f2b(v);
}

// ---------------- paper bias sums ----------------
__global__ void bsum_kernel(const float* __restrict__ bl, float* __restrict__ bsum_p) {
    int t = threadIdx.x;  // 256
    int l = t >> 7, i = t & 127;
    bsum_p[t] = bl[(long)(l * 5 + 0) * H + i] + bl[(long)(l * 5 + 1) * H + i] +
                bl[(long)(l * 5 + 2) * H + i];
}

// ---------------- combined CSR build over 5 concatenated relations ----------------
#define NPC 200000
#define NAC 100000
#define NVC 10000
#define EWC 2000000
#define EPC 200000
#define ETOT 6400000
#define NDEG 710000

__device__ __forceinline__ void edge_map(long e, const int* w, const int* c, const int* p,
                                         const int* rw, const int* rp2, int half,
                                         int& val, int& bse) {
    // half 0: src, half 1: dst
    if (e < 2 * EWC) {
        if (e < EWC) { val = w[e + (long)half * EWC]; bse = 0; }
        else { val = c[(e - EWC) + (long)half * EWC]; bse = NPC; }
    } else if (e < 2 * EWC + EPC) {
        val = p[(e - 2 * EWC) + (long)half * EPC]; bse = 2 * NPC;
    } else if (e < 3 * EWC + EPC) {
        val = rw[(e - 2 * EWC - EPC) + (long)half * EWC]; bse = 3 * NPC;
    } else {
        val = rp2[(e - 3 * EWC - EPC) + (long)half * EPC]; bse = 3 * NPC + NAC;
    }
}

__global__ void hist_all(const int* __restrict__ w, const int* __restrict__ c,
                         const int* __restrict__ p, const int* __restrict__ rw,
                         const int* __restrict__ rp2, int* __restrict__ deg) {
    long stride = (long)gridDim.x * blockDim.x;
    for (long e = (long)blockIdx.x * blockDim.x + threadIdx.x; e < ETOT; e += stride) {
        int d, b;
        edge_map(e, w, c, p, rw, rp2, 1, d, b);
        atomicAdd(&deg[b + d], 1);
    }
}

__global__ void fill_all(const int* __restrict__ w, const int* __restrict__ c,
                         const int* __restrict__ p, const int* __restrict__ rw,
                         const int* __restrict__ rp2, const int* __restrict__ gscan,
                         int* __restrict__ cursor, int* __restrict__ srcs_all) {
    long stride = (long)gridDim.x * blockDim.x;
    for (long e = (long)blockIdx.x * blockDim.x + threadIdx.x; e < ETOT; e += stride) {
        int d, b, s, b2;
        edge_map(e, w, c, p, rw, rp2, 1, d, b);
        edge_map(e, w, c, p, rw, rp2, 0, s, b2);
        int pos = atomicAdd(&cursor[b + d], 1);
        srcs_all[gscan[b + d] + pos] = s;
    }
}

__global__ void scan_reduce(const int* __restrict__ deg, int* __restrict__ bsum, int n) {
    __shared__ int sdata[256];
    int b = blockIdx.x, t = threadIdx.x;
    int base = b * 1024;
    int s = 0;
#pragma unroll
    for (int j = 0; j < 4; ++j) {
        int i = base + t * 4 + j;
        if (i < n) s += deg[i];
    }
    sdata[t] = s;
    __syncthreads();
    for (int o = 128; o > 0; o >>= 1) {
        if (t < o) sdata[t] += sdata[t + o];
        __syncthreads();
    }
    if (t == 0) bsum[b] = sdata[0];
}

__global__ void scan_bsum(int* __restrict__ bsum, int nb) {
    if (threadIdx.x == 0 && blockIdx.x == 0) {
        int acc = 0;
        for (int i = 0; i < nb; ++i) {
            int v = bsum[i];
            bsum[i] = acc;
            acc += v;
        }
    }
}

__global__ void scan_final(const int* __restrict__ deg, const int* __restrict__ bsum,
                           int* __restrict__ row_ptr, int n, int E) {
    __shared__ int ssum[256];
    int b = blockIdx.x, t = threadIdx.x;
    int base = b * 1024;
    int v[4];
    int s = 0;
#pragma unroll
    for (int j = 0; j < 4; ++j) {
        int i = base + t * 4 + j;
        v[j] = (i < n) ? deg[i] : 0;
        s += v[j];
    }
    ssum[t] = s;
    __syncthreads();
    for (int o = 1; o < 256; o <<= 1) {
        int x = (t >= o) ? ssum[t - o] : 0;
        __syncthreads();
        ssum[t] += x;
        __syncthreads();
    }
    int excl = bsum[b] + ((t > 0) ? ssum[t - 1] : 0);
#pragma unroll
    for (int j = 0; j < 4; ++j) {
        int i = base + t * 4 + j;
        if (i < n) {
            row_ptr[i] = excl;
            excl += v[j];
        }
    }
    if (b == 0 && t == 0) row_ptr[n] = E;
}

// ---------------- gather core: mean of neighbor rows, 4 rows per VMEM request ----------------
__device__ __forceinline__ void gather_row(const u16* __restrict__ xs,
                                           const int* __restrict__ ss,
                                           int beg, int end, u16* __restrict__ outp,
                                           int lane) {
    int q = lane >> 4, l16 = lane & 15;
    float ax[8];
#pragma unroll
    for (int i = 0; i < 8; ++i) ax[i] = 0.f;

    for (int c = beg; c < end; c += 64) {
        int m = end - c;
        if (m > 64) m = 64;
        int idx = (lane < m) ? ss[c + lane] : 0;
        for (int jj = 0; jj < m; jj += 4) {
            int s = __shfl(idx, jj + q, 64);
            if (jj + q < m) {
                const uint4 v = *reinterpret_cast<const uint4*>(xs + (long)s * H + l16 * 8);
                ax[0] += b2f((u16)(v.x & 0xffff)); ax[1] += b2f((u16)(v.x >> 16));
                ax[2] += b2f((u16)(v.y & 0xffff)); ax[3] += b2f((u16)(v.y >> 16));
                ax[4] += b2f((u16)(v.z & 0xffff)); ax[5] += b2f((u16)(v.z >> 16));
                ax[6] += b2f((u16)(v.w & 0xffff)); ax[7] += b2f((u16)(v.w >> 16));
            }
        }
    }
#pragma unroll
    for (int i = 0; i < 8; ++i) {
        ax[i] += __shfl_xor(ax[i], 32, 64);
        ax[i] += __shfl_xor(ax[i], 16, 64);
    }
    if (q == 0) {
        float inv = 1.0f / fmaxf((float)(end - beg), 1.0f);
        uint4 o;
        o.x = (unsigned)f2b(ax[0] * inv) | ((unsigned)f2b(ax[1] * inv) << 16);
        o.y = (unsigned)f2b(ax[2] * inv) | ((unsigned)f2b(ax[3] * inv) << 16);
        o.z = (unsigned)f2b(ax[4] * inv) | ((unsigned)f2b(ax[5] * inv) << 16);
        o.w = (unsigned)f2b(ax[6] * inv) | ((unsigned)f2b(ax[7] * inv) << 16);
        *reinterpret_cast<uint4*>(outp + l16 * 8) = o;
    }
}

// generic single-relation gather (fallback path)
__global__ void gather_mean4(const u16* __restrict__ xs,
                             const int* __restrict__ rp,
                             const int* __restrict__ ss,
                             u16* __restrict__ out, int n_dst) {
    long gid = (long)blockIdx.x * blockDim.x + threadIdx.x;
    int w = (int)(gid >> 6);
    if (w >= n_dst) return;
    int lane = (int)(gid & 63);
    gather_row(xs, ss, rp[w], rp[w + 1], out + (long)w * H, lane);
}

// fused 3-relation paper gather: waves 0..3*NPC over contiguous gscan[0..3*NPC]
__global__ void gather_paper3(const u16* __restrict__ xa, const u16* __restrict__ xp,
                              const u16* __restrict__ xv,
                              const int* __restrict__ rp, const int* __restrict__ ss,
                              u16* __restrict__ agg0, u16* __restrict__ agg1,
                              u16* __restrict__ agg2) {
    long gid = (long)blockIdx.x * blockDim.x + threadIdx.x;
    int w = (int)(gid >> 6);  // 0..600000
    int lane = (int)(gid & 63);
    const u16* xs;
    u16* out;
    int r;
    if (w < NPC)            { xs = xa; out = agg0; r = w; }
    else if (w < 2 * NPC)   { xs = xp; out = agg1; r = w - NPC; }
    else                    { xs = xv; out = agg2; r = w - 2 * NPC; }
    gather_row(xs, ss, rp[w], rp[w + 1], out + (long)r * H, lane);
}

// fused author+venue gather: waves 0..NAC+NVC over contiguous gscan[3*NPC ..]
// author rows -> out[0..NAC), venue rows -> out[row_off_v + 0..NVC)
__global__ void gather_av(const u16* __restrict__ xp,
                          const int* __restrict__ rp, const int* __restrict__ ss,
                          u16* __restrict__ out, int row_off_v) {
    long gid = (long)blockIdx.x * blockDim.x + threadIdx.x;
    int w = (int)(gid >> 6);  // 0..110000
    int lane = (int)(gid & 63);
    int r = (w < NAC) ? w : (row_off_v + (w - NAC));
    gather_row(xp, ss, rp[w], rp[w + 1], out + (long)r * H, lane);
}

// ---------------- multi-source MFMA GEMM: acc = sum_s A_s @ W_s (+Yin), epilogue ----------------
__global__ __launch_bounds__(256) void mfma_gemm_multi(
    int n_dst, int nsrc,
    const u16* __restrict__ A0, const u16* __restrict__ W0,
    const u16* __restrict__ A1, const u16* __restrict__ W1,
    const u16* __restrict__ A2, const u16* __restrict__ W2,
    const u16* __restrict__ A3, const u16* __restrict__ W3,
    const float* __restrict__ bias, float scale,
    const float* __restrict__ Yin, float* __restrict__ Yraw,
    float* __restrict__ yf, u16* __restrict__ yb) {
    const int t = threadIdx.x;
    const int lane = t & 63;
    const int w = t >> 6;
    const int wr = w >> 1, wc = w & 1;
    const long base = (long)blockIdx.x * 128;
    const int hi = (lane >> 4) & 3;
    const int lo = lane & 15;

    f32x4 acc[4][4];
#pragma unroll
    for (int i = 0; i < 4; ++i)
#pragma unroll
        for (int j = 0; j < 4; ++j) acc[i][j] = (f32x4){0.f, 0.f, 0.f, 0.f};

    for (int p = 0; p < nsrc; ++p) {
        const u16* A = (p == 0) ? A0 : (p == 1) ? A1 : (p == 2) ? A2 : A3;
        const u16* W = (p == 0) ? W0 : (p == 1) ? W1 : (p == 2) ? W2 : W3;
#pragma unroll
        for (int ks = 0; ks < 4; ++ks) {
            bf16x8 a[4];
#pragma unroll
            for (int fr = 0; fr < 4; ++fr) {
                long r = base + wr * 64 + fr * 16 + lo;
                a[fr] = *reinterpret_cast<const bf16x8*>(A + r * H + ks * 32 + hi * 8);
            }
#pragma unroll
            for (int fc = 0; fc < 4; ++fc) {
                int nb = wc * 4 + fc;
                bf16x8 b = *reinterpret_cast<const bf16x8*>(W + ((ks * 8 + nb) * 512 + lane * 8));
#pragma unroll
                for (int fr = 0; fr < 4; ++fr)
                    acc[fr][fc] = __builtin_amdgcn_mfma_f32_16x16x32_bf16(a[fr], b, acc[fr][fc], 0, 0, 0);
            }
        }
    }

#pragma unroll
    for (int fc = 0; fc < 4; ++fc) {
        int col = wc * 64 + fc * 16 + lo;
#pragma unroll
        for (int fr = 0; fr < 4; ++fr) {
#pragma unroll
            for (int i = 0; i < 4; ++i) {
                long g = base + wr * 64 + fr * 16 + hi * 4 + i;
                if (g < n_dst) {
                    float v = acc[fr][fc][i];
                    if (Yin) v += Yin[g * H + col];
                    if (Yraw) {
                        Yraw[g * H + col] = v;
                    } else {
                        float val = fmaxf((v + bias[col]) * scale, 0.f);
                        if (yf) yf[g * H + col] = val;
                        else    yb[g * H + col] = f2b(val);
                    }
                }
            }
        }
    }
}

extern "C" void kernel_launch(void* const* d_in, const int* in_sizes, int n_in,
                              void* d_out, int out_size, void* d_ws, size_t ws_size,
                              hipStream_t stream) {
    const float* xp0 = (const float*)d_in[0];
    const float* xa0 = (const float*)d_in[1];
    const float* xv0 = (const float*)d_in[2];
    const float* Wl  = (const float*)d_in[3];
    const float* bl  = (const float*)d_in[4];
    const float* Wr  = (const float*)d_in[5];
    const int* ei_w  = (const int*)d_in[6];
    const int* ei_c  = (const int*)d_in[7];
    const int* ei_p  = (const int*)d_in[8];
    const int* ei_rw = (const int*)d_in[9];
    const int* ei_rp = (const int*)d_in[10];

    const long NP = 200000, NA = 100000, NV = 10000;
    const long NPp = 200064, NAp = 100096, NVp = 10112;

    const size_t NEED_FULL = 344316508 + 4096;
    const bool full = ws_size >= NEED_FULL;

    char* cur = (char*)d_ws;
    auto alloc = [&](long bytes) { char* r = cur; cur += (bytes + 255) & ~255L; return r; };
    u16* xpb   = (u16*)alloc(NPp * H * 2);
    u16* xab   = (u16*)alloc(NAp * H * 2);
    u16* xvb   = (u16*)alloc(NVp * H * 2);
    u16* xp1b  = (u16*)alloc(NPp * H * 2);
    u16* xa1b  = (u16*)alloc(NAp * H * 2);
    u16* xv1b  = (u16*)alloc(NVp * H * 2);
    u16* agg0  = (u16*)alloc(NPp * H * 2);
    u16* agg1  = full ? (u16*)alloc(NPp * H * 2) : nullptr;
    u16* agg2  = full ? (u16*)alloc(NPp * H * 2) : nullptr;
    u16* packw = (u16*)alloc(16 * 16384 * 2);
    float* bsum_p = (float*)alloc(256 * 4);
    int* gscan    = (int*)alloc((NDEG + 1) * 4);
    int* deg      = (int*)alloc(NDEG * 4);
    int* srcs_all = (int*)alloc((long)ETOT * 4);
    int* bsums    = (int*)alloc(((NDEG + 1023) / 1024) * 4);

    float* op = (float*)d_out;
    float* oa = op + NP * H;
    float* ov = oa + NA * H;

    // ---- prep: casts, weight pack, bias sums ----
    cast_kernel<<<2048, 256, 0, stream>>>(xp0, xpb, NP * H / 4);
    cast_kernel<<<1024, 256, 0, stream>>>(xa0, xab, NA * H / 4);
    cast_kernel<<<256, 256, 0, stream>>>(xv0, xvb, NV * H / 4);
    pack_kernel<<<1024, 256, 0, stream>>>(Wl, Wr, packw);
    bsum_kernel<<<1, 256, 0, stream>>>(bl, bsum_p);

    // ---- combined CSR build (R5 proven path) ----
    hipMemsetAsync(deg, 0, NDEG * 4, stream);
    hist_all<<<2048, 256, 0, stream>>>(ei_w, ei_c, ei_p, ei_rw, ei_rp, deg);
    int nb = (NDEG + 1023) / 1024;
    scan_reduce<<<nb, 256, 0, stream>>>(deg, bsums, NDEG);
    scan_bsum<<<1, 64, 0, stream>>>(bsums, nb);
    scan_final<<<nb, 256, 0, stream>>>(deg, bsums, gscan, NDEG, ETOT);
    hipMemsetAsync(deg, 0, NDEG * 4, stream);
    fill_all<<<2048, 256, 0, stream>>>(ei_w, ei_c, ei_p, ei_rw, ei_rp, gscan, deg, srcs_all);

    const int* rp_w  = gscan;
    const int* rp_c  = gscan + NP;
    const int* rp_p  = gscan + 2 * NP;
    const int* rp_av = gscan + 3 * NP;
    const int* rp_rw = gscan + 3 * NP;
    const int* rp_rp = gscan + 3 * NP + NA;

    auto PW = [&](int l, int m) { return packw + (long)(l * 8 + m) * 16384; };
    auto GV = [&](long n) { return (int)((n * 64 + 255) / 256); };
    auto GT = [&](long np) { return (int)(np / 128); };
    const u16* NU = nullptr;

    auto run_layer = [&](int l, const u16* xp, const u16* xa, const u16* xv,
                         float* Yp, float* yfp, u16* ybp,
                         float* yfa, u16* yba, float* yfv, u16* ybv) {
        if (full) {
            // fused paper gather (3 relations, one dispatch)
            gather_paper3<<<GV(3 * NP), 256, 0, stream>>>(xa, xp, xv, gscan, srcs_all,
                                                          agg0, agg1, agg2);
            mfma_gemm_multi<<<GT(NPp), 256, 0, stream>>>(
                (int)NP, 4, xp, PW(l, 3), agg0, PW(l, 0), agg1, PW(l, 1), agg2, PW(l, 2),
                bsum_p + l * 128, 1.0f / 3.0f, nullptr, nullptr, yfp, ybp);
            // fused author+venue gather: author -> agg0[0..NA), venue -> agg0[NAp..)
            gather_av<<<GV(NA + NV), 256, 0, stream>>>(xp, rp_av, srcs_all, agg0, (int)NAp);
            mfma_gemm_multi<<<GT(NAp), 256, 0, stream>>>(
                (int)NA, 2, xa, PW(l, 5), agg0, PW(l, 4), NU, NU, NU, NU,
                bl + (long)(l * 5 + 3) * H, 1.0f, nullptr, nullptr, yfa, yba);
            mfma_gemm_multi<<<GT(NVp), 256, 0, stream>>>(
                (int)NV, 2, xv, PW(l, 7), agg0 + NAp * H, PW(l, 6), NU, NU, NU, NU,
                bl + (long)(l * 5 + 4) * H, 1.0f, nullptr, nullptr, yfv, ybv);
        } else {
            gather_mean4<<<GV(NP), 256, 0, stream>>>(xa, rp_w, srcs_all, agg0, (int)NP);
            mfma_gemm_multi<<<GT(NPp), 256, 0, stream>>>(
                (int)NP, 2, xp, PW(l, 3), agg0, PW(l, 0), NU, NU, NU, NU,
                nullptr, 0.f, nullptr, Yp, nullptr, nullptr);
            gather_mean4<<<GV(NP), 256, 0, stream>>>(xp, rp_c, srcs_all, agg0, (int)NP);
            mfma_gemm_multi<<<GT(NPp), 256, 0, stream>>>(
                (int)NP, 1, agg0, PW(l, 1), NU, NU, NU, NU, NU, NU,
                nullptr, 0.f, Yp, Yp, nullptr, nullptr);
            gather_mean4<<<GV(NP), 256, 0, stream>>>(xv, rp_p, srcs_all, agg0, (int)NP);
            mfma_gemm_multi<<<GT(NPp), 256, 0, stream>>>(
                (int)NP, 1, agg0, PW(l, 2), NU, NU, NU, NU, NU, NU,
                bsum_p + l * 128, 1.0f / 3.0f, Yp, nullptr, yfp, ybp);
            gather_mean4<<<GV(NA), 256, 0, stream>>>(xp, rp_rw, srcs_all, agg0, (int)NA);
            mfma_gemm_multi<<<GT(NAp), 256, 0, stream>>>(
                (int)NA, 2, xa, PW(l, 5), agg0, PW(l, 4), NU, NU, NU, NU,
                bl + (long)(l * 5 + 3) * H, 1.0f, nullptr, nullptr, yfa, yba);
            gather_mean4<<<GV(NV), 256, 0, stream>>>(xp, rp_rp, srcs_all, agg0, (int)NV);
            mfma_gemm_multi<<<GT(NVp), 256, 0, stream>>>(
                (int)NV, 2, xv, PW(l, 7), agg0, PW(l, 6), NU, NU, NU, NU,
                bl + (long)(l * 5 + 4) * H, 1.0f, nullptr, nullptr, yfv, ybv);
        }
    };

    run_layer(0, xpb, xab, xvb, op, nullptr, xp1b, nullptr, xa1b, nullptr, xv1b);
    run_layer(1, xp1b, xa1b, xv1b, op, op, nullptr, oa, nullptr, ov, nullptr);
}

// Round 10
// 1556.835 us; speedup vs baseline: 1.7065x; 1.1233x over previous
//
#include <hip/hip_runtime.h>

#define H 128
typedef unsigned short u16;
typedef __attribute__((ext_vector_type(8))) short bf16x8;
typedef __attribute__((ext_vector_type(4))) float f32x4;

#define NPC 200000
#define NAC 100000
#define NVC 10000
#define EWC 2000000
#define EPC 200000
#define ETOT 6400000
#define NDEG 710000
#define NPP 200064
#define NAP 100096
#define NVP 10112
#define TP 1563
#define TA 782
#define TV 79

__device__ __forceinline__ u16 f2b(float f) {
    unsigned u = __builtin_bit_cast(unsigned, f);
    unsigned r = (u + 0x7fff + ((u >> 16) & 1)) >> 16;
    return (u16)r;
}
__device__ __forceinline__ float b2f(u16 b) {
    unsigned u = ((unsigned)b) << 16;
    return __builtin_bit_cast(float, u);
}

// ---------------- cast f32 -> bf16 ----------------
__global__ void cast_kernel(const float* __restrict__ in, u16* __restrict__ out, long n4) {
    long stride = (long)gridDim.x * blockDim.x;
    for (long i = (long)blockIdx.x * blockDim.x + threadIdx.x; i < n4; i += stride) {
        float4 v = reinterpret_cast<const float4*>(in)[i];
        ushort4 o;
        o.x = f2b(v.x); o.y = f2b(v.y); o.z = f2b(v.z); o.w = f2b(v.w);
        reinterpret_cast<ushort4*>(out)[i] = o;
    }
}

// ---------------- pack weights into MFMA B-fragment layout (bf16) ----------------
// jobs m: 0-2: Wl[l,m]; 3: sum Wr[l,0..2]; 4: Wl[l,3]; 5: Wr[l,3]; 6: Wl[l,4]; 7: Wr[l,4]
__global__ void pack_kernel(const float* __restrict__ Wl, const float* __restrict__ Wr,
                            u16* __restrict__ out) {
    int tid = blockIdx.x * blockDim.x + threadIdx.x;  // 16*16384
    int e = tid & 16383;
    int job = tid >> 14;
    int l = job >> 3, m = job & 7;
    int lane = (e >> 3) & 63;
    int j = e & 7;
    int knb = e >> 9;  // 0..31
    int k = (knb >> 3) * 32 + ((lane >> 4) & 3) * 8 + j;
    int n = (knb & 7) * 16 + (lane & 15);
    long off = (long)k * H + n;
    float v;
    if (m < 3) v = Wl[((long)(l * 5 + m)) * (H * H) + off];
    else if (m == 3) v = Wr[((long)(l * 5 + 0)) * (H * H) + off] +
                         Wr[((long)(l * 5 + 1)) * (H * H) + off] +
                         Wr[((long)(l * 5 + 2)) * (H * H) + off];
    else if (m == 4) v = Wl[((long)(l * 5 + 3)) * (H * H) + off];
    else if (m == 5) v = Wr[((long)(l * 5 + 3)) * (H * H) + off];
    else if (m == 6) v = Wl[((long)(l * 5 + 4)) * (H * H) + off];
    else             v = Wr[((long)(l * 5 + 4)) * (H * H) + off];
    out[(long)job * 16384 + e] = f2b(v);
}

// ---------------- paper bias sums ----------------
__global__ void bsum_kernel(const float* __restrict__ bl, float* __restrict__ bsum_p) {
    int t = threadIdx.x;  // 256
    int l = t >> 7, i = t & 127;
    bsum_p[t] = bl[(long)(l * 5 + 0) * H + i] + bl[(long)(l * 5 + 1) * H + i] +
                bl[(long)(l * 5 + 2) * H + i];
}

// ---------------- combined CSR build (R5 proven path) ----------------
__device__ __forceinline__ void edge_map(long e, const int* w, const int* c, const int* p,
                                         const int* rw, const int* rp2, int half,
                                         int& val, int& bse) {
    if (e < 2 * EWC) {
        if (e < EWC) { val = w[e + (long)half * EWC]; bse = 0; }
        else { val = c[(e - EWC) + (long)half * EWC]; bse = NPC; }
    } else if (e < 2 * EWC + EPC) {
        val = p[(e - 2 * EWC) + (long)half * EPC]; bse = 2 * NPC;
    } else if (e < 3 * EWC + EPC) {
        val = rw[(e - 2 * EWC - EPC) + (long)half * EWC]; bse = 3 * NPC;
    } else {
        val = rp2[(e - 3 * EWC - EPC) + (long)half * EPC]; bse = 3 * NPC + NAC;
    }
}

__global__ void hist_all(const int* __restrict__ w, const int* __restrict__ c,
                         const int* __restrict__ p, const int* __restrict__ rw,
                         const int* __restrict__ rp2, int* __restrict__ deg) {
    long stride = (long)gridDim.x * blockDim.x;
    for (long e = (long)blockIdx.x * blockDim.x + threadIdx.x; e < ETOT; e += stride) {
        int d, b;
        edge_map(e, w, c, p, rw, rp2, 1, d, b);
        atomicAdd(&deg[b + d], 1);
    }
}

__global__ void fill_all(const int* __restrict__ w, const int* __restrict__ c,
                         const int* __restrict__ p, const int* __restrict__ rw,
                         const int* __restrict__ rp2, const int* __restrict__ gscan,
                         int* __restrict__ cursor, int* __restrict__ srcs_all) {
    long stride = (long)gridDim.x * blockDim.x;
    for (long e = (long)blockIdx.x * blockDim.x + threadIdx.x; e < ETOT; e += stride) {
        int d, b, s, b2;
        edge_map(e, w, c, p, rw, rp2, 1, d, b);
        edge_map(e, w, c, p, rw, rp2, 0, s, b2);
        int pos = atomicAdd(&cursor[b + d], 1);
        srcs_all[gscan[b + d] + pos] = s;
    }
}

__global__ void scan_reduce(const int* __restrict__ deg, int* __restrict__ bsum, int n) {
    __shared__ int sdata[256];
    int b = blockIdx.x, t = threadIdx.x;
    int base = b * 1024;
    int s = 0;
#pragma unroll
    for (int j = 0; j < 4; ++j) {
        int i = base + t * 4 + j;
        if (i < n) s += deg[i];
    }
    sdata[t] = s;
    __syncthreads();
    for (int o = 128; o > 0; o >>= 1) {
        if (t < o) sdata[t] += sdata[t + o];
        __syncthreads();
    }
    if (t == 0) bsum[b] = sdata[0];
}

__global__ void scan_bsum(int* __restrict__ bsum, int nb) {
    if (threadIdx.x == 0 && blockIdx.x == 0) {
        int acc = 0;
        for (int i = 0; i < nb; ++i) {
            int v = bsum[i];
            bsum[i] = acc;
            acc += v;
        }
    }
}

__global__ void scan_final(const int* __restrict__ deg, const int* __restrict__ bsum,
                           int* __restrict__ row_ptr, int n, int E) {
    __shared__ int ssum[256];
    int b = blockIdx.x, t = threadIdx.x;
    int base = b * 1024;
    int v[4];
    int s = 0;
#pragma unroll
    for (int j = 0; j < 4; ++j) {
        int i = base + t * 4 + j;
        v[j] = (i < n) ? deg[i] : 0;
        s += v[j];
    }
    ssum[t] = s;
    __syncthreads();
    for (int o = 1; o < 256; o <<= 1) {
        int x = (t >= o) ? ssum[t - o] : 0;
        __syncthreads();
        ssum[t] += x;
        __syncthreads();
    }
    int excl = bsum[b] + ((t > 0) ? ssum[t - 1] : 0);
#pragma unroll
    for (int j = 0; j < 4; ++j) {
        int i = base + t * 4 + j;
        if (i < n) {
            row_ptr[i] = excl;
            excl += v[j];
        }
    }
    if (b == 0 && t == 0) row_ptr[n] = E;
}

// ---------------- zgemm4: 4-job batched MFMA GEMM, Z = A @ W -> bf16 ----------------
__global__ __launch_bounds__(256) void zgemm4(
    const u16* __restrict__ a0, const u16* __restrict__ w0, u16* __restrict__ o0, int t0,
    const u16* __restrict__ a1, const u16* __restrict__ w1, u16* __restrict__ o1, int t1,
    const u16* __restrict__ a2, const u16* __restrict__ w2, u16* __restrict__ o2, int t2,
    const u16* __restrict__ a3, const u16* __restrict__ w3, u16* __restrict__ o3) {
    int b = blockIdx.x;
    const u16 *A, *W;
    u16* O;
    int lb;
    if (b < t0)                { A = a0; W = w0; O = o0; lb = b; }
    else if (b < t0 + t1)      { A = a1; W = w1; O = o1; lb = b - t0; }
    else if (b < t0 + t1 + t2) { A = a2; W = w2; O = o2; lb = b - t0 - t1; }
    else                       { A = a3; W = w3; O = o3; lb = b - t0 - t1 - t2; }

    const int t = threadIdx.x;
    const int lane = t & 63;
    const int w = t >> 6;
    const int wr = w >> 1, wc = w & 1;
    const long base = (long)lb * 128;
    const int hi = (lane >> 4) & 3;
    const int lo = lane & 15;

    f32x4 acc[4][4];
#pragma unroll
    for (int i = 0; i < 4; ++i)
#pragma unroll
        for (int j = 0; j < 4; ++j) acc[i][j] = (f32x4){0.f, 0.f, 0.f, 0.f};

#pragma unroll
    for (int ks = 0; ks < 4; ++ks) {
        bf16x8 a[4];
#pragma unroll
        for (int fr = 0; fr < 4; ++fr) {
            long r = base + wr * 64 + fr * 16 + lo;
            a[fr] = *reinterpret_cast<const bf16x8*>(A + r * H + ks * 32 + hi * 8);
        }
#pragma unroll
        for (int fc = 0; fc < 4; ++fc) {
            int nb = wc * 4 + fc;
            bf16x8 bb = *reinterpret_cast<const bf16x8*>(W + ((ks * 8 + nb) * 512 + lane * 8));
#pragma unroll
            for (int fr = 0; fr < 4; ++fr)
                acc[fr][fc] = __builtin_amdgcn_mfma_f32_16x16x32_bf16(a[fr], bb, acc[fr][fc], 0, 0, 0);
        }
    }

#pragma unroll
    for (int fc = 0; fc < 4; ++fc) {
        int col = wc * 64 + fc * 16 + lo;
#pragma unroll
        for (int fr = 0; fr < 4; ++fr) {
#pragma unroll
            for (int i = 0; i < 4; ++i) {
                long g = base + wr * 64 + fr * 16 + hi * 4 + i;
                O[g * H + col] = f2b(acc[fr][fc][i]);
            }
        }
    }
}

// ---------------- final gather core: ax += mean over CSR segment of Z rows ----------------
__device__ __forceinline__ void acc_mean(const u16* __restrict__ z,
                                         const int* __restrict__ ss,
                                         int beg, int end, int lane, int q, int l16,
                                         float ax[8]) {
    float t[8];
#pragma unroll
    for (int i = 0; i < 8; ++i) t[i] = 0.f;
    for (int c = beg; c < end; c += 64) {
        int m = end - c;
        if (m > 64) m = 64;
        int idx = (lane < m) ? ss[c + lane] : 0;
        for (int jj = 0; jj < m; jj += 4) {
            int s = __shfl(idx, jj + q, 64);
            if (jj + q < m) {
                const uint4 v = *reinterpret_cast<const uint4*>(z + (long)s * H + l16 * 8);
                t[0] += b2f((u16)(v.x & 0xffff)); t[1] += b2f((u16)(v.x >> 16));
                t[2] += b2f((u16)(v.y & 0xffff)); t[3] += b2f((u16)(v.y >> 16));
                t[4] += b2f((u16)(v.z & 0xffff)); t[5] += b2f((u16)(v.z >> 16));
                t[6] += b2f((u16)(v.w & 0xffff)); t[7] += b2f((u16)(v.w >> 16));
            }
        }
    }
    float inv = 1.0f / fmaxf((float)(end - beg), 1.0f);
#pragma unroll
    for (int i = 0; i < 8; ++i) ax[i] += t[i] * inv;
}

__device__ __forceinline__ void final_write(float ax[8], const u16* zself, long w,
                                            const float* __restrict__ bias, float scale,
                                            float* yf, u16* yb, int lane, int q, int l16) {
#pragma unroll
    for (int i = 0; i < 8; ++i) {
        ax[i] += __shfl_xor(ax[i], 32, 64);
        ax[i] += __shfl_xor(ax[i], 16, 64);
    }
    if (q == 0) {
        const uint4 sv = *reinterpret_cast<const uint4*>(zself + w * H + l16 * 8);
        float se[8] = {b2f((u16)(sv.x & 0xffff)), b2f((u16)(sv.x >> 16)),
                       b2f((u16)(sv.y & 0xffff)), b2f((u16)(sv.y >> 16)),
                       b2f((u16)(sv.z & 0xffff)), b2f((u16)(sv.z >> 16)),
                       b2f((u16)(sv.w & 0xffff)), b2f((u16)(sv.w >> 16))};
        const float4 b0 = *reinterpret_cast<const float4*>(bias + l16 * 8);
        const float4 b1 = *reinterpret_cast<const float4*>(bias + l16 * 8 + 4);
        float bb[8] = {b0.x, b0.y, b0.z, b0.w, b1.x, b1.y, b1.z, b1.w};
        float o[8];
#pragma unroll
        for (int i = 0; i < 8; ++i) o[i] = fmaxf((ax[i] + se[i] + bb[i]) * scale, 0.f);
        if (yf) {
            float* yp = yf + w * H + l16 * 8;
            *reinterpret_cast<float4*>(yp) = make_float4(o[0], o[1], o[2], o[3]);
            *reinterpret_cast<float4*>(yp + 4) = make_float4(o[4], o[5], o[6], o[7]);
        } else {
            uint4 ov;
            ov.x = (unsigned)f2b(o[0]) | ((unsigned)f2b(o[1]) << 16);
            ov.y = (unsigned)f2b(o[2]) | ((unsigned)f2b(o[3]) << 16);
            ov.z = (unsigned)f2b(o[4]) | ((unsigned)f2b(o[5]) << 16);
            ov.w = (unsigned)f2b(o[6]) | ((unsigned)f2b(o[7]) << 16);
            *reinterpret_cast<uint4*>(yb + w * H + l16 * 8) = ov;
        }
    }
}

// paper: 3 relations + self, scale 1/3
__global__ void final_paper(const u16* __restrict__ z0, const u16* __restrict__ z1,
                            const u16* __restrict__ z2, const u16* __restrict__ zps,
                            const int* __restrict__ gs, const int* __restrict__ ss,
                            const float* __restrict__ bias,
                            float* yf, u16* yb) {
    long gid = (long)blockIdx.x * blockDim.x + threadIdx.x;
    long w = gid >> 6;
    if (w >= NPC) return;
    int lane = (int)(gid & 63), q = lane >> 4, l16 = lane & 15;
    float ax[8] = {0.f, 0.f, 0.f, 0.f, 0.f, 0.f, 0.f, 0.f};
    acc_mean(z0, ss, gs[w], gs[w + 1], lane, q, l16, ax);
    acc_mean(z1, ss, gs[NPC + w], gs[NPC + w + 1], lane, q, l16, ax);
    acc_mean(z2, ss, gs[2 * NPC + w], gs[2 * NPC + w + 1], lane, q, l16, ax);
    final_write(ax, zps, w, bias, 1.0f / 3.0f, yf, yb, lane, q, l16);
}

// author + venue fused: 1 relation + self each, scale 1
__global__ void final_av(const u16* __restrict__ z3, const u16* __restrict__ zas,
                         const u16* __restrict__ z4, const u16* __restrict__ zvs,
                         const int* __restrict__ rp, const int* __restrict__ ss,
                         const float* __restrict__ bias3, const float* __restrict__ bias4,
                         float* yfa, u16* yba, float* yfv, u16* ybv) {
    long gid = (long)blockIdx.x * blockDim.x + threadIdx.x;
    long w = gid >> 6;
    if (w >= NAC + NVC) return;
    int lane = (int)(gid & 63), q = lane >> 4, l16 = lane & 15;
    float ax[8] = {0.f, 0.f, 0.f, 0.f, 0.f, 0.f, 0.f, 0.f};
    if (w < NAC) {
        acc_mean(z3, ss, rp[w], rp[w + 1], lane, q, l16, ax);
        final_write(ax, zas, w, bias3, 1.0f, yfa, yba, lane, q, l16);
    } else {
        long wv = w - NAC;
        acc_mean(z4, ss, rp[NAC + wv], rp[NAC + wv + 1], lane, q, l16, ax);
        final_write(ax, zvs, wv, bias4, 1.0f, yfv, ybv, lane, q, l16);
    }
}

extern "C" void kernel_launch(void* const* d_in, const int* in_sizes, int n_in,
                              void* d_out, int out_size, void* d_ws, size_t ws_size,
                              hipStream_t stream) {
    const float* xp0 = (const float*)d_in[0];
    const float* xa0 = (const float*)d_in[1];
    const float* xv0 = (const float*)d_in[2];
    const float* Wl  = (const float*)d_in[3];
    const float* bl  = (const float*)d_in[4];
    const float* Wr  = (const float*)d_in[5];
    const int* ei_w  = (const int*)d_in[6];
    const int* ei_c  = (const int*)d_in[7];
    const int* ei_p  = (const int*)d_in[8];
    const int* ei_rw = (const int*)d_in[9];
    const int* ei_rp = (const int*)d_in[10];

    char* cur = (char*)d_ws;
    auto alloc = [&](long bytes) { char* r = cur; cur += (bytes + 255) & ~255L; return r; };
    u16* xpb   = (u16*)alloc((long)NPP * H * 2);
    u16* xab   = (u16*)alloc((long)NAP * H * 2);
    u16* xvb   = (u16*)alloc((long)NVP * H * 2);
    u16* packw = (u16*)alloc(16 * 16384 * 2);
    float* bsum_p = (float*)alloc(256 * 4);
    int* gscan    = (int*)alloc((NDEG + 1) * 4);
    int* deg      = (int*)alloc(NDEG * 4);
    int* srcs_all = (int*)alloc((long)ETOT * 4);
    int* bsums    = (int*)alloc(((NDEG + 1023) / 1024) * 4);
    u16* Z        = (u16*)alloc((long)(2 * NPP + NAP + NVP) * H * 2);  // 130.6 MB phase region

    // Z job pointers (shared across phases)
    u16* zj0 = Z;                                   // NPP rows (zps / z3)
    u16* zj1 = Z + (long)NPP * H;                   // NAP rows (z0 / zas)
    u16* zj2 = Z + (long)(NPP + NAP) * H;           // NPP rows (z1 / z4)
    u16* zj3 = Z + (long)(2 * NPP + NAP) * H;       // NVP rows (z2 / zvs)

    // layer-0 output stage in d_out (bf16), overwritten last by layer-1 paper final
    u16* sp = (u16*)d_out;
    u16* sa = sp + (long)NPP * H;
    u16* sv = sa + (long)NAP * H;

    float* op = (float*)d_out;
    float* oa = op + (long)NPC * H;
    float* ov = oa + (long)NAC * H;

    // ---- prep ----
    cast_kernel<<<2048, 256, 0, stream>>>(xp0, xpb, (long)NPC * H / 4);
    cast_kernel<<<1024, 256, 0, stream>>>(xa0, xab, (long)NAC * H / 4);
    cast_kernel<<<256, 256, 0, stream>>>(xv0, xvb, (long)NVC * H / 4);
    pack_kernel<<<1024, 256, 0, stream>>>(Wl, Wr, packw);
    bsum_kernel<<<1, 256, 0, stream>>>(bl, bsum_p);

    // ---- CSR build (R5 proven path) ----
    hipMemsetAsync(deg, 0, NDEG * 4, stream);
    hist_all<<<2048, 256, 0, stream>>>(ei_w, ei_c, ei_p, ei_rw, ei_rp, deg);
    int nb = (NDEG + 1023) / 1024;
    scan_reduce<<<nb, 256, 0, stream>>>(deg, bsums, NDEG);
    scan_bsum<<<1, 64, 0, stream>>>(bsums, nb);
    scan_final<<<nb, 256, 0, stream>>>(deg, bsums, gscan, NDEG, ETOT);
    hipMemsetAsync(deg, 0, NDEG * 4, stream);
    fill_all<<<2048, 256, 0, stream>>>(ei_w, ei_c, ei_p, ei_rw, ei_rp, gscan, deg, srcs_all);

    auto PW = [&](int l, int m) { return packw + (long)(l * 8 + m) * 16384; };
    const int NT = TP + TA + TP + TV;  // 3987
    auto GVB = [&](long n) { return (int)((n * 64 + 255) / 256); };

    auto run_layer = [&](int l, const u16* xp, const u16* xa, const u16* xv,
                         float* yfp, u16* ybp, float* yfa, u16* yba,
                         float* yfv, u16* ybv) {
        // phase BC: z3 = xp@Wl3, zas = xa@Wr3, z4 = xp@Wl4, zvs = xv@Wr4
        zgemm4<<<NT, 256, 0, stream>>>(xp, PW(l, 4), zj0, TP,
                                       xa, PW(l, 5), zj1, TA,
                                       xp, PW(l, 6), zj2, TP,
                                       xv, PW(l, 7), zj3);
        final_av<<<GVB(NAC + NVC), 256, 0, stream>>>(
            zj0, zj1, zj2, zj3, gscan + 3 * NPC, srcs_all,
            bl + (long)(l * 5 + 3) * H, bl + (long)(l * 5 + 4) * H,
            yfa, yba, yfv, ybv);
        // phase A: zps = xp@sumWr, z0 = xa@Wl0, z1 = xp@Wl1, z2 = xv@Wl2
        zgemm4<<<NT, 256, 0, stream>>>(xp, PW(l, 3), zj0, TP,
                                       xa, PW(l, 0), zj1, TA,
                                       xp, PW(l, 1), zj2, TP,
                                       xv, PW(l, 2), zj3);
        final_paper<<<GVB(NPC), 256, 0, stream>>>(
            zj1, zj2, zj3, zj0, gscan, srcs_all, bsum_p + l * 128, yfp, ybp);
    };

    // layer 0: bf16 outputs staged in d_out
    run_layer(0, xpb, xab, xvb, nullptr, sp, nullptr, sa, nullptr, sv);
    // layer 1: f32 outputs into d_out (paper final last, overwrites stage after all reads)
    run_layer(1, sp, sa, sv, op, nullptr, oa, nullptr, ov, nullptr);
}